// Round 5
// baseline (503.770 us; speedup 1.0000x reference)
//
#include <hip/hip_runtime.h>
#include <hip/hip_bf16.h>

#define ALPHA 0.2f

constexpr int BN   = 4;
constexpr int NN   = 4096;
constexpr int FIN  = 256;
constexpr int FOUT = 128;
constexpr int NT   = 64;                  // 64-row strips
constexpr int NPAIR = NT * (NT + 1) / 2;  // 2080 triangular pairs per batch

typedef __attribute__((ext_vector_type(8))) short bf16x8;
typedef __attribute__((ext_vector_type(4))) float f32x4;

#define MFMA16(a, b, c) __builtin_amdgcn_mfma_f32_16x16x32_bf16((a), (b), (c), 0, 0, 0)

// ---------- DPP 16-lane rotate-reduce (VALU, no DS pipe) ----------
template<int CTRL>
__device__ __forceinline__ float dpp_mov(float x) {
    return __int_as_float(__builtin_amdgcn_update_dpp(
        __float_as_int(x), __float_as_int(x), CTRL, 0xF, 0xF, false));
}
__device__ __forceinline__ float rsum16(float x) {
    x += dpp_mov<0x128>(x);   // row_ror:8
    x += dpp_mov<0x124>(x);   // row_ror:4
    x += dpp_mov<0x122>(x);   // row_ror:2
    x += dpp_mov<0x121>(x);   // row_ror:1
    return x;
}
__device__ __forceinline__ float rmax16(float x) {
    x = fmaxf(x, dpp_mov<0x128>(x));
    x = fmaxf(x, dpp_mov<0x124>(x));
    x = fmaxf(x, dpp_mov<0x122>(x));
    x = fmaxf(x, dpp_mov<0x121>(x));
    return x;
}

// ---------- split one fp32 octet into hi/lo bf16 granules ----------
__device__ __forceinline__ void split8(const float* x, uint4& H, uint4& L) {
    ushort hb[8], lb[8];
    #pragma unroll
    for (int i = 0; i < 8; ++i) {
        float xv = x[i];
        __hip_bfloat16 hh = __float2bfloat16(xv);
        float hf = __bfloat162float(hh);
        __hip_bfloat16 lw = __float2bfloat16(xv - hf);
        hb[i] = reinterpret_cast<const ushort&>(hh);
        lb[i] = reinterpret_cast<const ushort&>(lw);
    }
    H = make_uint4((uint)hb[0] | ((uint)hb[1] << 16), (uint)hb[2] | ((uint)hb[3] << 16),
                   (uint)hb[4] | ((uint)hb[5] << 16), (uint)hb[6] | ((uint)hb[7] << 16));
    L = make_uint4((uint)lb[0] | ((uint)lb[1] << 16), (uint)lb[2] | ((uint)lb[3] << 16),
                   (uint)lb[4] | ((uint)lb[5] << 16), (uint)lb[6] | ((uint)lb[7] << 16));
}

// ---------- k_hp helpers (LDS-staged GEMM, unchanged from R4 — verified) ----------
template<int ROWS, int KGSH>
__device__ __forceinline__ void stage_split(const float* __restrict__ src, int strideF,
                                            ushort* hi, ushort* lo, int tid) {
    constexpr int KG = 1 << KGSH;
    #pragma unroll
    for (int idx = tid; idx < ROWS * KG; idx += 256) {
        int row = idx >> KGSH, g = idx & (KG - 1);
        const float4* p4 = reinterpret_cast<const float4*>(src + (size_t)row * strideF + g * 8);
        float4 u = p4[0], v = p4[1];
        float x[8] = {u.x, u.y, u.z, u.w, v.x, v.y, v.z, v.w};
        uint4 H, L;
        split8(x, H, L);
        int gran = (row << KGSH) + (g ^ (row & 7));
        reinterpret_cast<uint4*>(hi)[gran] = H;
        reinterpret_cast<uint4*>(lo)[gran] = L;
    }
}
template<int ROWS, int KGSH>
__device__ __forceinline__ void stage_copy(const ushort* __restrict__ src, int strideU,
                                           ushort* dst, int tid) {
    constexpr int KG = 1 << KGSH;
    #pragma unroll
    for (int idx = tid; idx < ROWS * KG; idx += 256) {
        int row = idx >> KGSH, g = idx & (KG - 1);
        uint4 vv = *reinterpret_cast<const uint4*>(src + (size_t)row * strideU + g * 8);
        reinterpret_cast<uint4*>(dst)[(row << KGSH) + (g ^ (row & 7))] = vv;
    }
}
__device__ __forceinline__ bf16x8 frag16(const ushort* s, int rowbase, int kstep, int kgsh, int lane) {
    int r = rowbase + (lane & 15);
    int g = kstep * 4 + (lane >> 4);
    int gran = (r << kgsh) + (g ^ (r & 7));
    return *reinterpret_cast<const bf16x8*>(s + gran * 8);
}

// ---------------- K0: transpose + split W ----------------
__global__ void k_prepW(const float* __restrict__ W, ushort* __restrict__ Wt_hi,
                        ushort* __restrict__ Wt_lo) {
    int idx = blockIdx.x * 256 + threadIdx.x;
    if (idx >= FOUT * (FIN / 8)) return;
    int n = idx >> 5, g = idx & 31;
    float x[8];
    #pragma unroll
    for (int i = 0; i < 8; ++i) x[i] = W[(size_t)(g * 8 + i) * FOUT + n];
    uint4 H, L;
    split8(x, H, L);
    reinterpret_cast<uint4*>(Wt_hi)[n * 32 + g] = H;
    reinterpret_cast<uint4*>(Wt_lo)[n * 32 + g] = L;
}

// ---------------- K1: hp = h @ W; emits fp32 hp (d_out) + hp_hi/hp_lo ----------------
__global__ __launch_bounds__(256)
void k_hp(const float* __restrict__ h, const ushort* __restrict__ Wt_hi,
          const ushort* __restrict__ Wt_lo, float* __restrict__ hp,
          ushort* __restrict__ hp_hi, ushort* __restrict__ hp_lo) {
    __shared__ __align__(16) ushort Ah[64 * 64], Al[64 * 64];
    __shared__ __align__(16) ushort Bh[128 * 64], Bl[128 * 64];
    const int tid = threadIdx.x, lane = tid & 63, wid = tid >> 6;
    const int wy = wid >> 1, wx = wid & 1;
    const int ibase = blockIdx.x * 64;
    f32x4 z = {0.f, 0.f, 0.f, 0.f};
    f32x4 acc[2][4] = {{z, z, z, z}, {z, z, z, z}};
    for (int kt = 0; kt < 4; ++kt) {
        __syncthreads();
        stage_split<64, 3>(h + (size_t)ibase * FIN + kt * 64, FIN, Ah, Al, tid);
        stage_copy<128, 3>(Wt_hi + kt * 64, FIN, Bh, tid);
        stage_copy<128, 3>(Wt_lo + kt * 64, FIN, Bl, tid);
        __syncthreads();
        #pragma unroll
        for (int pr = 0; pr < 3; ++pr) {
            const ushort* A = (pr == 2) ? Al : Ah;
            const ushort* B = (pr == 1) ? Bl : Bh;
            #pragma unroll
            for (int ks = 0; ks < 2; ++ks) {
                bf16x8 a0 = frag16(A, wy * 32, ks, 3, lane);
                bf16x8 a1 = frag16(A, wy * 32 + 16, ks, 3, lane);
                #pragma unroll
                for (int c = 0; c < 4; ++c) {
                    bf16x8 bb = frag16(B, wx * 64 + c * 16, ks, 3, lane);
                    acc[0][c] = MFMA16(a0, bb, acc[0][c]);
                    acc[1][c] = MFMA16(a1, bb, acc[1][c]);
                }
            }
        }
    }
    #pragma unroll
    for (int r = 0; r < 2; ++r)
        #pragma unroll
        for (int c = 0; c < 4; ++c)
            #pragma unroll
            for (int p = 0; p < 4; ++p) {
                int row = ibase + wy * 32 + r * 16 + (lane >> 4) * 4 + p;
                int col = wx * 64 + c * 16 + (lane & 15);
                float x = acc[r][c][p];
                __hip_bfloat16 hh = __float2bfloat16(x);
                float hf = __bfloat162float(hh);
                __hip_bfloat16 lw = __float2bfloat16(x - hf);
                size_t off = (size_t)row * FOUT + col;
                hp[off] = x;
                hp_hi[off] = reinterpret_cast<const ushort&>(hh);
                hp_lo[off] = reinterpret_cast<const ushort&>(lw);
            }
}

// ---------- shared: per-wave task decode + 64x64 e-tile from GLOBAL fragments ----------
__device__ __forceinline__ void decode_task(int task, int& b, int& ti, int& tj) {
    b = task / NPAIR;
    int sub = task - b * NPAIR;
    int t = 0, width = NT;
    while (sub >= width) { sub -= width; --width; ++t; }
    ti = t;
    tj = t + sub;
}

// acc[r][c][p] = e[ibase + r*16 + (lane>>4)*4 + p][jbase + c*16 + (lane&15)]
__device__ __forceinline__ void etile_g(const ushort* __restrict__ Hh,
                                        const ushort* __restrict__ Hl,
                                        int ibase, int jbase, int lane,
                                        f32x4 acc[4][4]) {
    const int lrow = lane & 15, lg = lane >> 4;
    #pragma unroll
    for (int ks = 0; ks < 4; ++ks) {
        const int g8 = (ks * 4 + lg) * 8;
        bf16x8 aH[4], aL[4];
        #pragma unroll
        for (int r = 0; r < 4; ++r) {
            size_t off = (size_t)(ibase + r * 16 + lrow) * FOUT + g8;
            aH[r] = *reinterpret_cast<const bf16x8*>(Hh + off);
            aL[r] = *reinterpret_cast<const bf16x8*>(Hl + off);
        }
        #pragma unroll
        for (int c = 0; c < 4; ++c) {
            size_t off = (size_t)(jbase + c * 16 + lrow) * FOUT + g8;
            bf16x8 bH = *reinterpret_cast<const bf16x8*>(Hh + off);
            bf16x8 bL = *reinterpret_cast<const bf16x8*>(Hl + off);
            #pragma unroll
            for (int r = 0; r < 4; ++r) {
                acc[r][c] = MFMA16(aH[r], bH, acc[r][c]);
                acc[r][c] = MFMA16(aH[r], bL, acc[r][c]);
                acc[r][c] = MFMA16(aL[r], bH, acc[r][c]);
            }
        }
    }
}

// ---------------- K2: symmetric per-row (== per-col) max/sumexp partials ----------------
__global__ __launch_bounds__(256)
void k_stats(const ushort* __restrict__ hp_hi, const ushort* __restrict__ hp_lo,
             float* __restrict__ m_part, float* __restrict__ s_part) {
    const int tid = threadIdx.x, lane = tid & 63, wid = tid >> 6;
    const int lrow = lane & 15, lg = lane >> 4;
    int b, ti, tj;
    decode_task(blockIdx.x * 4 + wid, b, ti, tj);
    const size_t bo = (size_t)b * NN * FOUT;
    const int ibase = ti * 64, jbase = tj * 64;
    f32x4 z = {0.f, 0.f, 0.f, 0.f};
    f32x4 acc[4][4] = {{z,z,z,z},{z,z,z,z},{z,z,z,z},{z,z,z,z}};
    etile_g(hp_hi + bo, hp_lo + bo, ibase, jbase, lane, acc);
    // LeakyReLU in place
    #pragma unroll
    for (int r = 0; r < 4; ++r)
        #pragma unroll
        for (int c = 0; c < 4; ++c)
            #pragma unroll
            for (int p = 0; p < 4; ++p) {
                float x = acc[r][c][p];
                acc[r][c][p] = fmaxf(x, ALPHA * x);
            }
    // I-side: stats over j in this tile, for rows of strip ti -> slot tj
    {
        float* mp = m_part + (size_t)(b * NT + tj) * NN;
        float* sp = s_part + (size_t)(b * NT + tj) * NN;
        #pragma unroll
        for (int r = 0; r < 4; ++r)
            #pragma unroll
            for (int p = 0; p < 4; ++p) {
                float mx = fmaxf(fmaxf(acc[r][0][p], acc[r][1][p]),
                                 fmaxf(acc[r][2][p], acc[r][3][p]));
                mx = rmax16(mx);
                float se = 0.f;
                #pragma unroll
                for (int c = 0; c < 4; ++c) se += __expf(acc[r][c][p] - mx);
                se = rsum16(se);
                if (lrow == 0) {
                    int i = ibase + r * 16 + lg * 4 + p;
                    mp[i] = mx;
                    sp[i] = se;
                }
            }
    }
    // J-side (transpose contribution): stats over i, for rows of strip tj -> slot ti
    if (ti != tj) {
        float* mp = m_part + (size_t)(b * NT + ti) * NN;
        float* sp = s_part + (size_t)(b * NT + ti) * NN;
        #pragma unroll
        for (int c = 0; c < 4; ++c) {
            float mx = -1e30f;
            #pragma unroll
            for (int r = 0; r < 4; ++r)
                #pragma unroll
                for (int p = 0; p < 4; ++p) mx = fmaxf(mx, acc[r][c][p]);
            mx = fmaxf(mx, __shfl_xor(mx, 16));
            mx = fmaxf(mx, __shfl_xor(mx, 32));
            float se = 0.f;
            #pragma unroll
            for (int r = 0; r < 4; ++r)
                #pragma unroll
                for (int p = 0; p < 4; ++p) se += __expf(acc[r][c][p] - mx);
            se += __shfl_xor(se, 16);
            se += __shfl_xor(se, 32);
            if (lane < 16) {
                int j = jbase + c * 16 + lane;
                mp[j] = mx;
                sp[j] = se;
            }
        }
    }
}

// ---------------- K2b: merge the NT=64 partial slots ----------------
__global__ void k_merge(const float* __restrict__ m_part, const float* __restrict__ s_part,
                        float* __restrict__ m_fin, float* __restrict__ inv_s) {
    int idx = blockIdx.x * 256 + threadIdx.x;
    if (idx >= BN * NN) return;
    int b = idx >> 12, row = idx & (NN - 1);
    const float* mp = m_part + (size_t)b * NT * NN + row;
    const float* sp = s_part + (size_t)b * NT * NN + row;
    float M = -1e30f;
    for (int k = 0; k < NT; ++k) M = fmaxf(M, mp[(size_t)k * NN]);
    float S = 0.f;
    for (int k = 0; k < NT; ++k) S += sp[(size_t)k * NN] * __expf(mp[(size_t)k * NN] - M);
    m_fin[idx] = M;
    inv_s[idx] = 1.f / S;
}

// ---------------- K3: symmetric row-mass partials ----------------
__global__ __launch_bounds__(256)
void k_mass(const ushort* __restrict__ hp_hi, const ushort* __restrict__ hp_lo,
            const float* __restrict__ m_fin, const float* __restrict__ inv_s,
            float* __restrict__ rs_part) {
    const int tid = threadIdx.x, lane = tid & 63, wid = tid >> 6;
    const int lrow = lane & 15, lg = lane >> 4;
    int b, ti, tj;
    decode_task(blockIdx.x * 4 + wid, b, ti, tj);
    const size_t bo = (size_t)b * NN * FOUT;
    const int ibase = ti * 64, jbase = tj * 64;
    f32x4 z = {0.f, 0.f, 0.f, 0.f};
    f32x4 acc[4][4] = {{z,z,z,z},{z,z,z,z},{z,z,z,z},{z,z,z,z}};
    etile_g(hp_hi + bo, hp_lo + bo, ibase, jbase, lane, acc);
    const float* mf = m_fin + (size_t)b * NN;
    const float* isv = inv_s + (size_t)b * NN;
    float mj[4], sj[4];
    #pragma unroll
    for (int c = 0; c < 4; ++c) {
        int j = jbase + c * 16 + lrow;
        mj[c] = mf[j];
        sj[c] = isv[j];
    }
    // I-side: sum over j of exp(g - m_j)/s_j for rows of strip ti -> slot tj
    {
        float* rs = rs_part + (size_t)(b * NT + tj) * NN;
        #pragma unroll
        for (int r = 0; r < 4; ++r)
            #pragma unroll
            for (int p = 0; p < 4; ++p) {
                float s = 0.f;
                #pragma unroll
                for (int c = 0; c < 4; ++c) {
                    float x = acc[r][c][p];
                    float g = fmaxf(x, ALPHA * x);
                    s += __expf(g - mj[c]) * sj[c];
                }
                s = rsum16(s);
                if (lrow == 0) rs[ibase + r * 16 + lg * 4 + p] = s;
            }
    }
    // J-side (transpose): sum over i of exp(g - m_i)/s_i for rows of strip tj -> slot ti
    if (ti != tj) {
        float mi[4][4], si_[4][4];
        #pragma unroll
        for (int r = 0; r < 4; ++r)
            #pragma unroll
            for (int p = 0; p < 4; ++p) {
                int i = ibase + r * 16 + lg * 4 + p;
                mi[r][p] = mf[i];
                si_[r][p] = isv[i];
            }
        float* rs = rs_part + (size_t)(b * NT + ti) * NN;
        #pragma unroll
        for (int c = 0; c < 4; ++c) {
            float s2 = 0.f;
            #pragma unroll
            for (int r = 0; r < 4; ++r)
                #pragma unroll
                for (int p = 0; p < 4; ++p) {
                    float x = acc[r][c][p];
                    float g = fmaxf(x, ALPHA * x);
                    s2 += __expf(g - mi[r][p]) * si_[r][p];
                }
            s2 += __shfl_xor(s2, 16);
            s2 += __shfl_xor(s2, 32);
            if (lane < 16) rs[jbase + c * 16 + lane] = s2;
        }
    }
}

// ---------------- K4: out = hp * row_mass (merge NT rs slots, in place) ----------------
__global__ void k_scale(const float* __restrict__ rs_part, float* __restrict__ out) {
    int idx = blockIdx.x * 256 + threadIdx.x;
    if (idx >= BN * NN * FOUT / 4) return;
    int row = idx >> 5;                       // b*NN + i
    int b = row >> 12, i = row & (NN - 1);
    const float* rs = rs_part + (size_t)b * NT * NN + i;
    float rm = 0.f;
    for (int k = 0; k < NT; ++k) rm += rs[(size_t)k * NN];
    float4 v = reinterpret_cast<float4*>(out)[idx];
    v.x *= rm; v.y *= rm; v.z *= rm; v.w *= rm;
    reinterpret_cast<float4*>(out)[idx] = v;
}

extern "C" void kernel_launch(void* const* d_in, const int* in_sizes, int n_in,
                              void* d_out, int out_size, void* d_ws, size_t ws_size,
                              hipStream_t stream) {
    (void)in_sizes; (void)n_in; (void)out_size; (void)ws_size;
    const float* h = (const float*)d_in[0];
    // d_in[1] = adj (bool) — unused by the reference forward
    const float* W = (const float*)d_in[2];
    float* out = (float*)d_out;                    // doubles as hp (fp32)
    // workspace layout (~21 MB)
    ushort* hp_hi = (ushort*)d_ws;                               // BN*NN*FOUT
    ushort* hp_lo = hp_hi + (size_t)BN * NN * FOUT;              // BN*NN*FOUT
    ushort* Wt_hi = hp_lo + (size_t)BN * NN * FOUT;              // FOUT*FIN
    ushort* Wt_lo = Wt_hi + FOUT * FIN;                          // FOUT*FIN
    float* m_part = (float*)(Wt_lo + FOUT * FIN);                // BN*NT*NN
    float* s_part = m_part + (size_t)BN * NT * NN;               // BN*NT*NN
    float* m_fin  = s_part + (size_t)BN * NT * NN;               // BN*NN
    float* inv_s  = m_fin + (size_t)BN * NN;                     // BN*NN
    float* rs_part = inv_s + (size_t)BN * NN;                    // BN*NT*NN

    k_prepW<<<(FOUT * (FIN / 8) + 255) / 256, 256, 0, stream>>>(W, Wt_hi, Wt_lo);
    k_hp<<<BN * NN / 64, 256, 0, stream>>>(h, Wt_hi, Wt_lo, out, hp_hi, hp_lo);
    k_stats<<<BN * NPAIR / 4, 256, 0, stream>>>(hp_hi, hp_lo, m_part, s_part);
    k_merge<<<(BN * NN + 255) / 256, 256, 0, stream>>>(m_part, s_part, m_fin, inv_s);
    k_mass<<<BN * NPAIR / 4, 256, 0, stream>>>(hp_hi, hp_lo, m_fin, inv_s, rs_part);
    k_scale<<<(BN * NN * FOUT / 4 + 255) / 256, 256, 0, stream>>>(rs_part, out);
}

// Round 6
// 418.577 us; speedup vs baseline: 1.2035x; 1.2035x over previous
//
#include <hip/hip_runtime.h>
#include <hip/hip_bf16.h>

#define ALPHA 0.2f

constexpr int BN   = 4;
constexpr int NN   = 4096;
constexpr int FIN  = 256;
constexpr int FOUT = 128;
constexpr int NT   = 64;                  // 64-row strips
constexpr int NPAIR = NT * (NT + 1) / 2;  // 2080 triangular tile-pairs per batch

typedef __attribute__((ext_vector_type(8))) short bf16x8;
typedef __attribute__((ext_vector_type(4))) float f32x4;

#define MFMA16(a, b, c) __builtin_amdgcn_mfma_f32_16x16x32_bf16((a), (b), (c), 0, 0, 0)

// ---------- DPP 16-lane rotate-reduce (VALU, no DS pipe) ----------
template<int CTRL>
__device__ __forceinline__ float dpp_mov(float x) {
    return __int_as_float(__builtin_amdgcn_update_dpp(
        __float_as_int(x), __float_as_int(x), CTRL, 0xF, 0xF, false));
}
__device__ __forceinline__ float rsum16(float x) {
    x += dpp_mov<0x128>(x);   // row_ror:8
    x += dpp_mov<0x124>(x);   // row_ror:4
    x += dpp_mov<0x122>(x);   // row_ror:2
    x += dpp_mov<0x121>(x);   // row_ror:1
    return x;
}
__device__ __forceinline__ float rmax16(float x) {
    x = fmaxf(x, dpp_mov<0x128>(x));
    x = fmaxf(x, dpp_mov<0x124>(x));
    x = fmaxf(x, dpp_mov<0x122>(x));
    x = fmaxf(x, dpp_mov<0x121>(x));
    return x;
}

// ---------- split one fp32 octet into hi/lo bf16 granules ----------
__device__ __forceinline__ void split8(const float* x, uint4& H, uint4& L) {
    ushort hb[8], lb[8];
    #pragma unroll
    for (int i = 0; i < 8; ++i) {
        float xv = x[i];
        __hip_bfloat16 hh = __float2bfloat16(xv);
        float hf = __bfloat162float(hh);
        __hip_bfloat16 lw = __float2bfloat16(xv - hf);
        hb[i] = reinterpret_cast<const ushort&>(hh);
        lb[i] = reinterpret_cast<const ushort&>(lw);
    }
    H = make_uint4((uint)hb[0] | ((uint)hb[1] << 16), (uint)hb[2] | ((uint)hb[3] << 16),
                   (uint)hb[4] | ((uint)hb[5] << 16), (uint)hb[6] | ((uint)hb[7] << 16));
    L = make_uint4((uint)lb[0] | ((uint)lb[1] << 16), (uint)lb[2] | ((uint)lb[3] << 16),
                   (uint)lb[4] | ((uint)lb[5] << 16), (uint)lb[6] | ((uint)lb[7] << 16));
}

// ---------- k_hp LDS helpers (verified R2-R5) ----------
template<int ROWS, int KGSH>
__device__ __forceinline__ void stage_split(const float* __restrict__ src, int strideF,
                                            ushort* hi, ushort* lo, int tid) {
    constexpr int KG = 1 << KGSH;
    #pragma unroll
    for (int idx = tid; idx < ROWS * KG; idx += 256) {
        int row = idx >> KGSH, g = idx & (KG - 1);
        const float4* p4 = reinterpret_cast<const float4*>(src + (size_t)row * strideF + g * 8);
        float4 u = p4[0], v = p4[1];
        float x[8] = {u.x, u.y, u.z, u.w, v.x, v.y, v.z, v.w};
        uint4 H, L;
        split8(x, H, L);
        int gran = (row << KGSH) + (g ^ (row & 7));
        reinterpret_cast<uint4*>(hi)[gran] = H;
        reinterpret_cast<uint4*>(lo)[gran] = L;
    }
}
template<int ROWS, int KGSH>
__device__ __forceinline__ void stage_copy(const ushort* __restrict__ src, int strideU,
                                           ushort* dst, int tid) {
    constexpr int KG = 1 << KGSH;
    #pragma unroll
    for (int idx = tid; idx < ROWS * KG; idx += 256) {
        int row = idx >> KGSH, g = idx & (KG - 1);
        uint4 vv = *reinterpret_cast<const uint4*>(src + (size_t)row * strideU + g * 8);
        reinterpret_cast<uint4*>(dst)[(row << KGSH) + (g ^ (row & 7))] = vv;
    }
}
__device__ __forceinline__ bf16x8 frag16(const ushort* s, int rowbase, int kstep, int kgsh, int lane) {
    int r = rowbase + (lane & 15);
    int g = kstep * 4 + (lane >> 4);
    int gran = (r << kgsh) + (g ^ (r & 7));
    return *reinterpret_cast<const bf16x8*>(s + gran * 8);
}

// ---------------- K0: transpose + split W ----------------
__global__ void k_prepW(const float* __restrict__ W, ushort* __restrict__ Wt_hi,
                        ushort* __restrict__ Wt_lo) {
    int idx = blockIdx.x * 256 + threadIdx.x;
    if (idx >= FOUT * (FIN / 8)) return;
    int n = idx >> 5, g = idx & 31;
    float x[8];
    #pragma unroll
    for (int i = 0; i < 8; ++i) x[i] = W[(size_t)(g * 8 + i) * FOUT + n];
    uint4 H, L;
    split8(x, H, L);
    reinterpret_cast<uint4*>(Wt_hi)[n * 32 + g] = H;
    reinterpret_cast<uint4*>(Wt_lo)[n * 32 + g] = L;
}

// ---------------- K1: hp = h @ W (fp32 out only) ----------------
__global__ __launch_bounds__(256)
void k_hp(const float* __restrict__ h, const ushort* __restrict__ Wt_hi,
          const ushort* __restrict__ Wt_lo, float* __restrict__ hp) {
    __shared__ __align__(16) ushort Ah[64 * 64], Al[64 * 64];
    __shared__ __align__(16) ushort Bh[128 * 64], Bl[128 * 64];
    const int tid = threadIdx.x, lane = tid & 63, wid = tid >> 6;
    const int wy = wid >> 1, wx = wid & 1;
    const int ibase = blockIdx.x * 64;
    f32x4 z = {0.f, 0.f, 0.f, 0.f};
    f32x4 acc[2][4] = {{z, z, z, z}, {z, z, z, z}};
    for (int kt = 0; kt < 4; ++kt) {
        __syncthreads();
        stage_split<64, 3>(h + (size_t)ibase * FIN + kt * 64, FIN, Ah, Al, tid);
        stage_copy<128, 3>(Wt_hi + kt * 64, FIN, Bh, tid);
        stage_copy<128, 3>(Wt_lo + kt * 64, FIN, Bl, tid);
        __syncthreads();
        #pragma unroll
        for (int pr = 0; pr < 3; ++pr) {
            const ushort* A = (pr == 2) ? Al : Ah;
            const ushort* B = (pr == 1) ? Bl : Bh;
            #pragma unroll
            for (int ks = 0; ks < 2; ++ks) {
                bf16x8 a0 = frag16(A, wy * 32, ks, 3, lane);
                bf16x8 a1 = frag16(A, wy * 32 + 16, ks, 3, lane);
                #pragma unroll
                for (int c = 0; c < 4; ++c) {
                    bf16x8 bb = frag16(B, wx * 64 + c * 16, ks, 3, lane);
                    acc[0][c] = MFMA16(a0, bb, acc[0][c]);
                    acc[1][c] = MFMA16(a1, bb, acc[1][c]);
                }
            }
        }
    }
    #pragma unroll
    for (int r = 0; r < 2; ++r)
        #pragma unroll
        for (int c = 0; c < 4; ++c)
            #pragma unroll
            for (int p = 0; p < 4; ++p) {
                int row = ibase + wy * 32 + r * 16 + (lane >> 4) * 4 + p;
                int col = wx * 64 + c * 16 + (lane & 15);
                hp[(size_t)row * FOUT + col] = acc[r][c][p];
            }
}

// ---------------- K1b: pack hp -> fragment-linear hi/lo ----------------
// chunk (b, panel P, slice ks, lane l) at uint4 index ((b*256+P)*4+ks)*64+l
// holds hp[b][P*16 + (l&15)][(ks*4 + (l>>4))*8 .. +8) as bf16 hi/lo.
__global__ void k_fragpack(const float* __restrict__ hp, ushort* __restrict__ hi,
                           ushort* __restrict__ lo) {
    int t = blockIdx.x * 256 + threadIdx.x;      // BN*256*4*64 = 262144
    int l = t & 63, ks = (t >> 6) & 3, P = (t >> 8) & 255, b = t >> 16;
    int row = P * 16 + (l & 15), c8 = ks * 4 + (l >> 4);
    const float* src = hp + ((size_t)b * NN + row) * FOUT + c8 * 8;
    const float4* p4 = reinterpret_cast<const float4*>(src);
    float4 u = p4[0], v = p4[1];
    float x[8] = {u.x, u.y, u.z, u.w, v.x, v.y, v.z, v.w};
    uint4 H, L;
    split8(x, H, L);
    size_t o = (((size_t)b * 256 + P) * 4 + ks) * 64 + l;
    reinterpret_cast<uint4*>(hi)[o] = H;
    reinterpret_cast<uint4*>(lo)[o] = L;
}

// ---------- task decode: XCD-pinned (batch -> XCD pair), triangular pair ----------
__device__ __forceinline__ void decode2(int bid, int wid, int& b, int& ti, int& tj) {
    int slot = bid & 7;
    b = slot >> 1;
    int sub = ((bid >> 3) << 1) | (slot & 1);    // 0..519 within batch
    int tb = sub * 4 + wid;                      // 0..2079
    int t = 0, width = NT;
    while (tb >= width) { tb -= width; --width; ++t; }
    ti = t;
    tj = t + tb;
}

// ---------- 64x64 e-tile from fragment-linear global (fully coalesced) ----------
// acc[r][c][p] = e[ti*64 + r*16 + (lane>>4)*4 + p][tj*64 + c*16 + (lane&15)]
__device__ __forceinline__ void etile_fl(const uint4* __restrict__ H4,
                                         const uint4* __restrict__ L4,
                                         int pi, int pj, int lane, f32x4 acc[4][4]) {
    #pragma unroll
    for (int ks = 0; ks < 4; ++ks) {
        bf16x8 aH[4], aL[4];
        #pragma unroll
        for (int r = 0; r < 4; ++r) {
            size_t idx = ((size_t)(pi + r) * 4 + ks) * 64 + lane;
            aH[r] = *reinterpret_cast<const bf16x8*>(&H4[idx]);
            aL[r] = *reinterpret_cast<const bf16x8*>(&L4[idx]);
        }
        #pragma unroll
        for (int c = 0; c < 4; ++c) {
            size_t jdx = ((size_t)(pj + c) * 4 + ks) * 64 + lane;
            bf16x8 bH = *reinterpret_cast<const bf16x8*>(&H4[jdx]);
            bf16x8 bL = *reinterpret_cast<const bf16x8*>(&L4[jdx]);
            #pragma unroll
            for (int r = 0; r < 4; ++r) {
                acc[r][c] = MFMA16(aH[r], bH, acc[r][c]);
                acc[r][c] = MFMA16(aH[r], bL, acc[r][c]);
                acc[r][c] = MFMA16(aL[r], bH, acc[r][c]);
            }
        }
    }
}

// ---------------- K2: symmetric per-row (== per-col) max/sumexp partials ----------------
__global__ __launch_bounds__(256, 3)
void k_stats(const ushort* __restrict__ hp_hi, const ushort* __restrict__ hp_lo,
             float* __restrict__ m_part, float* __restrict__ s_part) {
    const int tid = threadIdx.x, lane = tid & 63, wid = tid >> 6;
    const int lrow = lane & 15, lg = lane >> 4;
    int b, ti, tj;
    decode2(blockIdx.x, wid, b, ti, tj);
    const uint4* H4 = reinterpret_cast<const uint4*>(hp_hi) + (size_t)b * 256 * 256;
    const uint4* L4 = reinterpret_cast<const uint4*>(hp_lo) + (size_t)b * 256 * 256;
    const int ibase = ti * 64, jbase = tj * 64;
    f32x4 z = {0.f, 0.f, 0.f, 0.f};
    f32x4 acc[4][4] = {{z,z,z,z},{z,z,z,z},{z,z,z,z},{z,z,z,z}};
    etile_fl(H4, L4, ti * 4, tj * 4, lane, acc);
    #pragma unroll
    for (int r = 0; r < 4; ++r)
        #pragma unroll
        for (int c = 0; c < 4; ++c)
            #pragma unroll
            for (int p = 0; p < 4; ++p) {
                float x = acc[r][c][p];
                acc[r][c][p] = fmaxf(x, ALPHA * x);   // LeakyReLU
            }
    // I-side: reduce over j (16 cols per lane-row group) for rows of strip ti -> slot tj
    {
        float* mp = m_part + (size_t)(b * NT + tj) * NN;
        float* sp = s_part + (size_t)(b * NT + tj) * NN;
        #pragma unroll
        for (int r = 0; r < 4; ++r)
            #pragma unroll
            for (int p = 0; p < 4; ++p) {
                float mx = fmaxf(fmaxf(acc[r][0][p], acc[r][1][p]),
                                 fmaxf(acc[r][2][p], acc[r][3][p]));
                mx = rmax16(mx);
                float se = 0.f;
                #pragma unroll
                for (int c = 0; c < 4; ++c) se += __expf(acc[r][c][p] - mx);
                se = rsum16(se);
                if (lrow == 0) {
                    int i = ibase + r * 16 + lg * 4 + p;
                    mp[i] = mx;
                    sp[i] = se;
                }
            }
    }
    // J-side (transpose contribution): reduce over i for cols of strip tj -> slot ti
    if (ti != tj) {
        float* mp = m_part + (size_t)(b * NT + ti) * NN;
        float* sp = s_part + (size_t)(b * NT + ti) * NN;
        #pragma unroll
        for (int c = 0; c < 4; ++c) {
            float mx = -1e30f;
            #pragma unroll
            for (int r = 0; r < 4; ++r)
                #pragma unroll
                for (int p = 0; p < 4; ++p) mx = fmaxf(mx, acc[r][c][p]);
            mx = fmaxf(mx, __shfl_xor(mx, 16));
            mx = fmaxf(mx, __shfl_xor(mx, 32));
            float se = 0.f;
            #pragma unroll
            for (int r = 0; r < 4; ++r)
                #pragma unroll
                for (int p = 0; p < 4; ++p) se += __expf(acc[r][c][p] - mx);
            se += __shfl_xor(se, 16);
            se += __shfl_xor(se, 32);
            if (lane < 16) {
                int j = jbase + c * 16 + lane;
                mp[j] = mx;
                sp[j] = se;
            }
        }
    }
}

// ---------------- K2b: merge the NT=64 partial slots ----------------
__global__ void k_merge(const float* __restrict__ m_part, const float* __restrict__ s_part,
                        float* __restrict__ m_fin, float* __restrict__ inv_s) {
    int idx = blockIdx.x * 256 + threadIdx.x;
    if (idx >= BN * NN) return;
    int b = idx >> 12, row = idx & (NN - 1);
    const float* mp = m_part + (size_t)b * NT * NN + row;
    const float* sp = s_part + (size_t)b * NT * NN + row;
    float M = -1e30f;
    for (int k = 0; k < NT; ++k) M = fmaxf(M, mp[(size_t)k * NN]);
    float S = 0.f;
    for (int k = 0; k < NT; ++k) S += sp[(size_t)k * NN] * __expf(mp[(size_t)k * NN] - M);
    m_fin[idx] = M;
    inv_s[idx] = 1.f / S;
}

// ---------------- K3: symmetric row-mass partials ----------------
__global__ __launch_bounds__(256, 3)
void k_mass(const ushort* __restrict__ hp_hi, const ushort* __restrict__ hp_lo,
            const float* __restrict__ m_fin, const float* __restrict__ inv_s,
            float* __restrict__ rs_part) {
    const int tid = threadIdx.x, lane = tid & 63, wid = tid >> 6;
    const int lrow = lane & 15, lg = lane >> 4;
    int b, ti, tj;
    decode2(blockIdx.x, wid, b, ti, tj);
    const uint4* H4 = reinterpret_cast<const uint4*>(hp_hi) + (size_t)b * 256 * 256;
    const uint4* L4 = reinterpret_cast<const uint4*>(hp_lo) + (size_t)b * 256 * 256;
    const int ibase = ti * 64, jbase = tj * 64;
    f32x4 z = {0.f, 0.f, 0.f, 0.f};
    f32x4 acc[4][4] = {{z,z,z,z},{z,z,z,z},{z,z,z,z},{z,z,z,z}};
    etile_fl(H4, L4, ti * 4, tj * 4, lane, acc);
    const float* mf = m_fin + (size_t)b * NN;
    const float* isv = inv_s + (size_t)b * NN;
    float mj[4], sj[4];
    #pragma unroll
    for (int c = 0; c < 4; ++c) {
        int j = jbase + c * 16 + lrow;
        mj[c] = mf[j];
        sj[c] = isv[j];
    }
    // I-side: sum_j exp(g - m_j) * inv_s_j for rows of strip ti -> slot tj
    {
        float* rs = rs_part + (size_t)(b * NT + tj) * NN;
        #pragma unroll
        for (int r = 0; r < 4; ++r)
            #pragma unroll
            for (int p = 0; p < 4; ++p) {
                float s = 0.f;
                #pragma unroll
                for (int c = 0; c < 4; ++c) {
                    float x = acc[r][c][p];
                    float g = fmaxf(x, ALPHA * x);
                    s += __expf(g - mj[c]) * sj[c];
                }
                s = rsum16(s);
                if (lrow == 0) rs[ibase + r * 16 + lg * 4 + p] = s;
            }
    }
    // J-side (transpose): sum_i exp(g - m_i) * inv_s_i for cols of strip tj -> slot ti
    if (ti != tj) {
        float mi[4][4], si_[4][4];
        #pragma unroll
        for (int r = 0; r < 4; ++r)
            #pragma unroll
            for (int p = 0; p < 4; ++p) {
                int i = ibase + r * 16 + lg * 4 + p;
                mi[r][p] = mf[i];
                si_[r][p] = isv[i];
            }
        float* rs = rs_part + (size_t)(b * NT + ti) * NN;
        #pragma unroll
        for (int c = 0; c < 4; ++c) {
            float s2 = 0.f;
            #pragma unroll
            for (int r = 0; r < 4; ++r)
                #pragma unroll
                for (int p = 0; p < 4; ++p) {
                    float x = acc[r][c][p];
                    float g = fmaxf(x, ALPHA * x);
                    s2 += __expf(g - mi[r][p]) * si_[r][p];
                }
            s2 += __shfl_xor(s2, 16);
            s2 += __shfl_xor(s2, 32);
            if (lane < 16) rs[jbase + c * 16 + lane] = s2;
        }
    }
}

// ---------------- K4: out = hp * row_mass (merge NT rs slots, in place) ----------------
__global__ void k_scale(const float* __restrict__ rs_part, float* __restrict__ out) {
    int idx = blockIdx.x * 256 + threadIdx.x;
    if (idx >= BN * NN * FOUT / 4) return;
    int row = idx >> 5;                       // b*NN + i
    int b = row >> 12, i = row & (NN - 1);
    const float* rs = rs_part + (size_t)b * NT * NN + i;
    float rm = 0.f;
    for (int k = 0; k < NT; ++k) rm += rs[(size_t)k * NN];
    float4 v = reinterpret_cast<float4*>(out)[idx];
    v.x *= rm; v.y *= rm; v.z *= rm; v.w *= rm;
    reinterpret_cast<float4*>(out)[idx] = v;
}

extern "C" void kernel_launch(void* const* d_in, const int* in_sizes, int n_in,
                              void* d_out, int out_size, void* d_ws, size_t ws_size,
                              hipStream_t stream) {
    (void)in_sizes; (void)n_in; (void)out_size; (void)ws_size;
    const float* h = (const float*)d_in[0];
    // d_in[1] = adj (bool) — unused by the reference forward
    const float* W = (const float*)d_in[2];
    float* out = (float*)d_out;                    // doubles as hp (fp32)
    // workspace layout (~21 MB)
    ushort* hp_hi = (ushort*)d_ws;                               // BN*NN*FOUT (frag-linear)
    ushort* hp_lo = hp_hi + (size_t)BN * NN * FOUT;              // BN*NN*FOUT
    ushort* Wt_hi = hp_lo + (size_t)BN * NN * FOUT;              // FOUT*FIN
    ushort* Wt_lo = Wt_hi + FOUT * FIN;                          // FOUT*FIN
    float* m_part = (float*)(Wt_lo + FOUT * FIN);                // BN*NT*NN
    float* s_part = m_part + (size_t)BN * NT * NN;               // BN*NT*NN
    float* m_fin  = s_part + (size_t)BN * NT * NN;               // BN*NN
    float* inv_s  = m_fin + (size_t)BN * NN;                     // BN*NN
    float* rs_part = inv_s + (size_t)BN * NN;                    // BN*NT*NN

    k_prepW<<<(FOUT * (FIN / 8) + 255) / 256, 256, 0, stream>>>(W, Wt_hi, Wt_lo);
    k_hp<<<BN * NN / 64, 256, 0, stream>>>(h, Wt_hi, Wt_lo, out);
    k_fragpack<<<BN * 256 * 4 * 64 / 256, 256, 0, stream>>>(out, hp_hi, hp_lo);
    k_stats<<<BN * NPAIR / 4, 256, 0, stream>>>(hp_hi, hp_lo, m_part, s_part);
    k_merge<<<(BN * NN + 255) / 256, 256, 0, stream>>>(m_part, s_part, m_fin, inv_s);
    k_mass<<<BN * NPAIR / 4, 256, 0, stream>>>(hp_hi, hp_lo, m_fin, inv_s, rs_part);
    k_scale<<<(BN * NN * FOUT / 4 + 255) / 256, 256, 0, stream>>>(rs_part, out);
}